// Round 4
// baseline (303.411 us; speedup 1.0000x reference)
//
#include <hip/hip_runtime.h>

#define Nn 4096
#define Mm 4096
#define Dd 512
#define Ee 128
#define KOUT 256
#define NBINS 4096
#define CAP 4096

// ---- workspace layout (bytes) ----
#define ROWSUM_OFF 0
#define COLSUM_OFF 16384
#define REN2_OFF   32768
#define SEN2_OFF   49152
#define HIST_OFF   65536
#define SCAN_OFF   81920
#define CNT_OFF    81928
#define CANDV_OFF  98304
#define CANDI_OFF  114688
// new path partials [4096][32] f32
#define RP32_OFF   131072
#define CP32_OFF   655360
// old fallback partials [4096][64]
#define ROWPART_OFF 131072
#define COLPART_OFF (131072 + 1048576)
// bf16 split arrays (new path): each 4096*640*2 = 5 MB
#define AH_OFF   4194304
#define AL_OFF   (AH_OFF + 5242880)
#define BH_OFF   (AL_OFF + 5242880)
#define BL_OFF   (BH_OFF + 5242880)
#define SNEW_OFF 25165824            // 24 MB, S = 64 MB -> ends 88 MB
#define NEW_REQ  ((size_t)SNEW_OFF + (size_t)Nn * Mm * 4)
// old fallback S at 4 MB
#define S_OFF      4194304
#define FAST_REQ   ((size_t)S_OFF + (size_t)Nn * Mm * 4)

typedef float f32x4 __attribute__((ext_vector_type(4)));
typedef __bf16 bf16x8 __attribute__((ext_vector_type(8)));

__global__ __launch_bounds__(256)
void zero_kernel(unsigned* __restrict__ wsu) {
    int i = blockIdx.x * 256 + threadIdx.x;
    if (i < NBINS + 3) wsu[HIST_OFF / 4 + i] = 0;
}

__global__ __launch_bounds__(64)
void norms_kernel(const float* __restrict__ re, const float* __restrict__ se,
                  float* __restrict__ ws) {
    int row = blockIdx.x;
    int t = threadIdx.x;
    const float* p = (row < Nn) ? (re + (size_t)row * Ee) : (se + (size_t)(row - Nn) * Ee);
    float x0 = p[t], x1 = p[t + 64];
    float v = x0 * x0 + x1 * x1;
    #pragma unroll
    for (int o = 32; o > 0; o >>= 1) v += __shfl_down(v, o);
    if (t == 0) {
        if (row < Nn) ws[REN2_OFF / 4 + row] = v;
        else          ws[SEN2_OFF / 4 + row - Nn] = v;
    }
}

// ---------------- MFMA path ----------------

__device__ __forceinline__ unsigned short b16rtn(float x) {
    unsigned u = __float_as_uint(x);
    return (unsigned short)((u + 0x7fffu + ((u >> 16) & 1u)) >> 16);
}
__device__ __forceinline__ void split1(float x, unsigned short& h, unsigned short& l) {
    h = b16rtn(x);
    float hf = __uint_as_float((unsigned)h << 16);
    l = b16rtn(x - hf);
}

__global__ __launch_bounds__(256)
void prep_kernel(const float* __restrict__ rf, const float* __restrict__ sf,
                 const float* __restrict__ re, const float* __restrict__ se,
                 unsigned short* __restrict__ AH, unsigned short* __restrict__ AL,
                 unsigned short* __restrict__ BH, unsigned short* __restrict__ BL) {
    int gt = blockIdx.x * 256 + threadIdx.x;
    int nth = gridDim.x * 256;
    const float4* rf4 = (const float4*)rf;
    const float4* sf4 = (const float4*)sf;
    const int Kc = Dd + Ee;
    for (int i = gt; i < Nn * Dd / 4; i += nth) {
        int r = i / (Dd / 4), c4 = i % (Dd / 4);
        size_t o = (size_t)r * Kc + c4 * 4;
        float4 a = rf4[i];
        ushort4 h, l;
        split1(a.x, h.x, l.x); split1(a.y, h.y, l.y);
        split1(a.z, h.z, l.z); split1(a.w, h.w, l.w);
        *(ushort4*)&AH[o] = h; *(ushort4*)&AL[o] = l;
        float4 b = sf4[i];
        split1(b.x, h.x, l.x); split1(b.y, h.y, l.y);
        split1(b.z, h.z, l.z); split1(b.w, h.w, l.w);
        *(ushort4*)&BH[o] = h; *(ushort4*)&BL[o] = l;
    }
    const float4* re4 = (const float4*)re;
    const float4* se4 = (const float4*)se;
    for (int i = gt; i < Nn * Ee / 4; i += nth) {
        int r = i / (Ee / 4), c4 = i % (Ee / 4);
        size_t o = (size_t)r * Kc + Dd + c4 * 4;
        float4 a = re4[i];
        ushort4 h, l;
        split1(a.x, h.x, l.x); split1(a.y, h.y, l.y);
        split1(a.z, h.z, l.z); split1(a.w, h.w, l.w);
        *(ushort4*)&AH[o] = h; *(ushort4*)&AL[o] = l;
        float4 b = se4[i];
        split1(0.1f * b.x, h.x, l.x); split1(0.1f * b.y, h.y, l.y);
        split1(0.1f * b.z, h.z, l.z); split1(0.1f * b.w, h.w, l.w);
        *(ushort4*)&BH[o] = h; *(ushort4*)&BL[o] = l;
    }
}

__device__ __forceinline__ void gload16(const void* g, void* l) {
    __builtin_amdgcn_global_load_lds((const __attribute__((address_space(1))) unsigned*)g,
                                     (__attribute__((address_space(3))) unsigned*)l, 16, 0, 0);
}

// Logical K = 1920: kt in [0,20) -> AH.BH, [20,40) -> AL.BH, [40,60) -> AH.BL.
// Epilogue: s = exp(acc - 0.05*(rn+cn) - 1); per-tile deterministic row/col sums; write S.
__global__ __launch_bounds__(256, 3)
void mfma_gemm_kernel(const __bf16* __restrict__ AH, const __bf16* __restrict__ AL,
                      const __bf16* __restrict__ BH, const __bf16* __restrict__ BL,
                      float* __restrict__ ws, float* __restrict__ S) {
    __shared__ __bf16 lds[2][2][4096];   // [dbuf][A/B][(g*128+r)*8]  = 32 KB
    const int tid = threadIdx.x;
    const int lane = tid & 63, wid = tid >> 6;
    const int bx = blockIdx.x, by = blockIdx.y;
    const int rowbase = by * 128, colbase = bx * 128;
    const int wr = wid >> 1, wc = wid & 1;

    // staging role: arr = A for wid 0/1, B for wid 2/3; each wave covers 2 of 4 k-groups
    const int sarr = wid >> 1;
    const int g0 = (wid & 1) * 2;
    const int srow = (sarr == 0) ? rowbase : colbase;

    f32x4 acc[4][4];
    #pragma unroll
    for (int i = 0; i < 4; ++i)
        #pragma unroll
        for (int j = 0; j < 4; ++j) acc[i][j] = (f32x4){0.f, 0.f, 0.f, 0.f};

    auto stage = [&](int buf, int kt) {
        const int seg = (kt >= 40) ? 2 : (kt >= 20) ? 1 : 0;
        const int kk = (kt - seg * 20) * 32;
        const __bf16* src = (sarr == 0) ? ((seg == 1) ? AL : AH)
                                        : ((seg == 2) ? BL : BH);
        #pragma unroll
        for (int t = 0; t < 4; ++t) {
            // flat = t*64 + lane; g = g0 + (flat>>7); r = flat & 127
            const int gt_ = g0 + (t >> 1);
            const int rt0 = (t & 1) * 64;
            gload16(src + (size_t)(srow + rt0 + lane) * 640 + kk + gt_ * 8,
                    (void*)&lds[buf][sarr][(gt_ * 128 + rt0) * 8]);
        }
    };

    stage(0, 0);
    const int g = lane >> 4, c = lane & 15;
    for (int kt = 0; kt < 60; ++kt) {
        const int buf = kt & 1;
        __syncthreads();
        if (kt + 1 < 60) stage(buf ^ 1, kt + 1);
        const __bf16* Asl = &lds[buf][0][0];
        const __bf16* Bsl = &lds[buf][1][0];
        bf16x8 a[4], b[4];
        #pragma unroll
        for (int mi = 0; mi < 4; ++mi)
            a[mi] = *(const bf16x8*)&Asl[(g * 128 + wr * 64 + mi * 16 + c) * 8];
        #pragma unroll
        for (int ni = 0; ni < 4; ++ni)
            b[ni] = *(const bf16x8*)&Bsl[(g * 128 + wc * 64 + ni * 16 + c) * 8];
        #pragma unroll
        for (int mi = 0; mi < 4; ++mi)
            #pragma unroll
            for (int ni = 0; ni < 4; ++ni)
                acc[mi][ni] = __builtin_amdgcn_mfma_f32_16x16x32_bf16(a[mi], b[ni], acc[mi][ni], 0, 0, 0);
    }
    __syncthreads();

    // epilogue
    float ren2v[4][4], sen2v[4];
    #pragma unroll
    for (int mi = 0; mi < 4; ++mi)
        #pragma unroll
        for (int q = 0; q < 4; ++q)
            ren2v[mi][q] = ws[REN2_OFF / 4 + rowbase + wr * 64 + mi * 16 + g * 4 + q];
    #pragma unroll
    for (int ni = 0; ni < 4; ++ni)
        sen2v[ni] = ws[SEN2_OFF / 4 + colbase + wc * 64 + ni * 16 + c];

    float* red = (float*)&lds[0][0][0];

    float colacc[4] = {0.f, 0.f, 0.f, 0.f};
    #pragma unroll
    for (int mi = 0; mi < 4; ++mi) {
        float rowacc[4] = {0.f, 0.f, 0.f, 0.f};
        #pragma unroll
        for (int ni = 0; ni < 4; ++ni) {
            #pragma unroll
            for (int q = 0; q < 4; ++q) {
                float e = acc[mi][ni][q] - 0.05f * (ren2v[mi][q] + sen2v[ni]) - 1.0f;
                float s = expf(e);
                acc[mi][ni][q] = s;
                rowacc[q] += s;
                colacc[ni] += s;
            }
        }
        #pragma unroll
        for (int q = 0; q < 4; ++q) {
            float v = rowacc[q];
            v += __shfl_xor(v, 1); v += __shfl_xor(v, 2);
            v += __shfl_xor(v, 4); v += __shfl_xor(v, 8);
            if (c == 0) red[wc * 128 + wr * 64 + mi * 16 + g * 4 + q] = v;
        }
    }
    #pragma unroll
    for (int ni = 0; ni < 4; ++ni) {
        float v = colacc[ni];
        v += __shfl_xor(v, 16); v += __shfl_xor(v, 32);
        if (g == 0) red[256 + wr * 128 + wc * 64 + ni * 16 + c] = v;
    }

    #pragma unroll
    for (int mi = 0; mi < 4; ++mi)
        #pragma unroll
        for (int q = 0; q < 4; ++q) {
            int r = rowbase + wr * 64 + mi * 16 + g * 4 + q;
            #pragma unroll
            for (int ni = 0; ni < 4; ++ni) {
                int cc = colbase + wc * 64 + ni * 16 + c;
                S[(size_t)r * Mm + cc] = acc[mi][ni][q];
            }
        }

    __syncthreads();
    if (tid < 128) {
        ws[RP32_OFF / 4 + (size_t)(rowbase + tid) * 32 + bx] = red[tid] + red[128 + tid];
    } else {
        int t2 = tid - 128;
        ws[CP32_OFF / 4 + (size_t)(colbase + t2) * 32 + by] = red[256 + t2] + red[384 + t2];
    }
}

__global__ __launch_bounds__(256)
void partred32_kernel(float* __restrict__ w) {
    int i = blockIdx.x * 256 + threadIdx.x;
    const float* rp = w + RP32_OFF / 4 + (size_t)i * 32;
    const float* cp = w + CP32_OFF / 4 + (size_t)i * 32;
    float a = 0.f, b = 0.f;
    #pragma unroll
    for (int k = 0; k < 32; ++k) { a += rp[k]; b += cp[k]; }
    w[ROWSUM_OFF / 4 + i] = a;
    w[COLSUM_OFF / 4 + i] = b;
}

// ---------------- old f32 fallback path (proven R2) ----------------

template <int MODE>
__global__ __launch_bounds__(256)
void tile_kernel(const float* __restrict__ rf, const float* __restrict__ sf,
                 const float* __restrict__ re, const float* __restrict__ se,
                 float* __restrict__ ws) {
    const int bx = blockIdx.x, by = blockIdx.y;
    const int tid = threadIdx.x;
    const int tx = tid & 15, ty = tid >> 4;
    const int rowbase = by * 64, colbase = bx * 64;

    __shared__ float As[16][68];
    __shared__ float Bs[16][68];

    float acc1[4][4] = {};
    float acc2[4][4] = {};

    for (int kk = 0; kk < Dd; kk += 16) {
        #pragma unroll
        for (int i = 0; i < 4; ++i) {
            int f = tid + i * 256;
            int r = f >> 4, c = f & 15;
            As[c][r] = rf[(size_t)(rowbase + r) * Dd + kk + c];
            Bs[c][r] = sf[(size_t)(colbase + r) * Dd + kk + c];
        }
        __syncthreads();
        #pragma unroll
        for (int k = 0; k < 16; ++k) {
            float a[4], b[4];
            #pragma unroll
            for (int i = 0; i < 4; ++i) a[i] = As[k][ty * 4 + i];
            #pragma unroll
            for (int j = 0; j < 4; ++j) b[j] = Bs[k][tx * 4 + j];
            #pragma unroll
            for (int i = 0; i < 4; ++i)
                #pragma unroll
                for (int j = 0; j < 4; ++j)
                    acc1[i][j] = fmaf(a[i], b[j], acc1[i][j]);
        }
        __syncthreads();
    }
    for (int kk = 0; kk < Ee; kk += 16) {
        #pragma unroll
        for (int i = 0; i < 4; ++i) {
            int f = tid + i * 256;
            int r = f >> 4, c = f & 15;
            As[c][r] = re[(size_t)(rowbase + r) * Ee + kk + c];
            Bs[c][r] = se[(size_t)(colbase + r) * Ee + kk + c];
        }
        __syncthreads();
        #pragma unroll
        for (int k = 0; k < 16; ++k) {
            float a[4], b[4];
            #pragma unroll
            for (int i = 0; i < 4; ++i) a[i] = As[k][ty * 4 + i];
            #pragma unroll
            for (int j = 0; j < 4; ++j) b[j] = Bs[k][tx * 4 + j];
            #pragma unroll
            for (int i = 0; i < 4; ++i)
                #pragma unroll
                for (int j = 0; j < 4; ++j)
                    acc2[i][j] = fmaf(a[i], b[j], acc2[i][j]);
        }
        __syncthreads();
    }

    const int r0 = rowbase + ty * 4, c0 = colbase + tx * 4;
    float rn[4], cn[4];
    #pragma unroll
    for (int i = 0; i < 4; ++i) rn[i] = ws[REN2_OFF / 4 + r0 + i];
    #pragma unroll
    for (int j = 0; j < 4; ++j) cn[j] = ws[SEN2_OFF / 4 + c0 + j];

    float s[4][4];
    #pragma unroll
    for (int i = 0; i < 4; ++i)
        #pragma unroll
        for (int j = 0; j < 4; ++j) {
            float d1 = fmaxf(2.0f - 2.0f * acc1[i][j], 0.0f);
            float sq = fmaxf(rn[i] + cn[j] - 2.0f * acc2[i][j], 0.0f);
            s[i][j] = expf(-(0.5f * d1 + 0.05f * sq));
        }

    if constexpr (MODE == 0) {
        float* S = ws + S_OFF / 4;
        #pragma unroll
        for (int i = 0; i < 4; ++i) {
            float4 v = make_float4(s[i][0], s[i][1], s[i][2], s[i][3]);
            *(float4*)&S[(size_t)(r0 + i) * Mm + c0] = v;
        }
    }
    if constexpr (MODE == 1) {
        __shared__ float red[64][17];
        #pragma unroll
        for (int i = 0; i < 4; ++i)
            red[ty * 4 + i][tx] = s[i][0] + s[i][1] + s[i][2] + s[i][3];
        __syncthreads();
        if (tid < 64) {
            float t = 0.f;
            #pragma unroll
            for (int k = 0; k < 16; ++k) t += red[tid][k];
            ws[ROWPART_OFF / 4 + (size_t)(rowbase + tid) * 64 + bx] = t;
        }
        __syncthreads();
        #pragma unroll
        for (int j = 0; j < 4; ++j)
            red[tx * 4 + j][ty] = s[0][j] + s[1][j] + s[2][j] + s[3][j];
        __syncthreads();
        if (tid < 64) {
            float t = 0.f;
            #pragma unroll
            for (int k = 0; k < 16; ++k) t += red[tid][k];
            ws[COLPART_OFF / 4 + (size_t)(colbase + tid) * 64 + by] = t;
        }
    }
    if constexpr (MODE == 2) {
        __shared__ unsigned lh[NBINS];
        for (int b = tid; b < NBINS; b += 256) lh[b] = 0;
        __syncthreads();
        float rs[4], cs[4];
        #pragma unroll
        for (int i = 0; i < 4; ++i) rs[i] = ws[ROWSUM_OFF / 4 + r0 + i];
        #pragma unroll
        for (int j = 0; j < 4; ++j) cs[j] = ws[COLSUM_OFF / 4 + c0 + j];
        #pragma unroll
        for (int i = 0; i < 4; ++i)
            #pragma unroll
            for (int j = 0; j < 4; ++j) {
                float f = (s[i][j] / rs[i]) * (s[i][j] / cs[j]);
                atomicAdd(&lh[__float_as_uint(f) >> 20], 1u);
            }
        __syncthreads();
        unsigned* hist = (unsigned*)ws + HIST_OFF / 4;
        for (int b = tid; b < NBINS; b += 256) {
            unsigned cc = lh[b];
            if (cc) atomicAdd(&hist[b], cc);
        }
    }
    if constexpr (MODE == 3) {
        unsigned tau = ((unsigned*)ws)[SCAN_OFF / 4];
        int* counter = (int*)ws + CNT_OFF / 4;
        float* candv = ws + CANDV_OFF / 4;
        int* candi = (int*)ws + CANDI_OFF / 4;
        float rs[4], cs[4];
        #pragma unroll
        for (int i = 0; i < 4; ++i) rs[i] = ws[ROWSUM_OFF / 4 + r0 + i];
        #pragma unroll
        for (int j = 0; j < 4; ++j) cs[j] = ws[COLSUM_OFF / 4 + c0 + j];
        #pragma unroll
        for (int i = 0; i < 4; ++i)
            #pragma unroll
            for (int j = 0; j < 4; ++j) {
                float f = (s[i][j] / rs[i]) * (s[i][j] / cs[j]);
                if (__float_as_uint(f) >= tau) {
                    int p = atomicAdd(counter, 1);
                    if (p < CAP) {
                        candv[p] = f;
                        candi[p] = (r0 + i) * Mm + (c0 + j);
                    }
                }
            }
    }
}

__global__ __launch_bounds__(256)
void partred_kernel(float* __restrict__ w) {
    int i = blockIdx.x * 256 + threadIdx.x;
    const float* rp = w + ROWPART_OFF / 4 + (size_t)i * 64;
    const float* cp = w + COLPART_OFF / 4 + (size_t)i * 64;
    float a = 0.f, b = 0.f;
    #pragma unroll
    for (int k = 0; k < 64; ++k) { a += rp[k]; b += cp[k]; }
    w[ROWSUM_OFF / 4 + i] = a;
    w[COLSUM_OFF / 4 + i] = b;
}

__global__ __launch_bounds__(256)
void rowsum_kernel(const float* __restrict__ S, float* __restrict__ ws) {
    int row = blockIdx.x;
    const float4* p = (const float4*)(S + (size_t)row * Mm);
    float acc = 0.f;
    #pragma unroll
    for (int k = 0; k < 4; ++k) {
        float4 v = p[threadIdx.x + k * 256];
        acc += v.x + v.y + v.z + v.w;
    }
    __shared__ float red[256];
    red[threadIdx.x] = acc;
    __syncthreads();
    for (int o = 128; o > 0; o >>= 1) {
        if (threadIdx.x < o) red[threadIdx.x] += red[threadIdx.x + o];
        __syncthreads();
    }
    if (threadIdx.x == 0) ws[ROWSUM_OFF / 4 + row] = red[0];
}

__global__ __launch_bounds__(256)
void colsum_kernel(const float* __restrict__ S, float* __restrict__ ws) {
    int base = blockIdx.x * 64;
    int c = threadIdx.x & 63, stripe = threadIdx.x >> 6;
    float acc = 0.f;
    for (int r = stripe; r < Nn; r += 4) acc += S[(size_t)r * Mm + base + c];
    __shared__ float red[256];
    red[threadIdx.x] = acc;
    __syncthreads();
    if (threadIdx.x < 64) {
        float t = red[c] + red[c + 64] + red[c + 128] + red[c + 192];
        ws[COLSUM_OFF / 4 + base + c] = t;
    }
}

// ---------------- shared selection pipeline ----------------

__global__ __launch_bounds__(256)
void hist_kernel(const float* __restrict__ S, float* __restrict__ ws) {
    __shared__ unsigned lh[NBINS];
    for (int b = threadIdx.x; b < NBINS; b += 256) lh[b] = 0;
    __syncthreads();
    const float* rowsum = ws + ROWSUM_OFF / 4;
    const float* colsum = ws + COLSUM_OFF / 4;
    unsigned* hist = (unsigned*)ws + HIST_OFF / 4;
    const float4* S4 = (const float4*)S;
    int gtid = blockIdx.x * 256 + threadIdx.x;
    const int total4 = Nn * Mm / 4;
    for (int idx = gtid; idx < total4; idx += gridDim.x * 256) {
        float4 v = S4[idx];
        int lin = idx * 4;
        int i = lin >> 12, j = lin & 4095;
        float ri = 1.0f / rowsum[i];
        float4 cv = *(const float4*)&colsum[j];
        float f0 = (v.x * ri) * (v.x / cv.x);
        float f1 = (v.y * ri) * (v.y / cv.y);
        float f2 = (v.z * ri) * (v.z / cv.z);
        float f3 = (v.w * ri) * (v.w / cv.w);
        atomicAdd(&lh[__float_as_uint(f0) >> 20], 1u);
        atomicAdd(&lh[__float_as_uint(f1) >> 20], 1u);
        atomicAdd(&lh[__float_as_uint(f2) >> 20], 1u);
        atomicAdd(&lh[__float_as_uint(f3) >> 20], 1u);
    }
    __syncthreads();
    for (int b = threadIdx.x; b < NBINS; b += 256) {
        unsigned c = lh[b];
        if (c) atomicAdd(&hist[b], c);
    }
}

__global__ __launch_bounds__(1024)
void scan_kernel(float* __restrict__ ws) {
    unsigned* hist = (unsigned*)ws + HIST_OFF / 4;
    unsigned* scano = (unsigned*)ws + SCAN_OFF / 4;
    __shared__ unsigned A[NBINS], B[NBINS];
    int t = threadIdx.x;
    for (int i = t; i < NBINS; i += 1024) A[i] = hist[NBINS - 1 - i];
    __syncthreads();
    unsigned* src = A;
    unsigned* dst = B;
    for (int st = 1; st < NBINS; st <<= 1) {
        for (int i = t; i < NBINS; i += 1024)
            dst[i] = src[i] + (i >= st ? src[i - st] : 0u);
        __syncthreads();
        unsigned* tmp = src; src = dst; dst = tmp;
    }
    for (int i = t; i < NBINS; i += 1024) {
        if (src[i] >= KOUT && (i == 0 || src[i - 1] < KOUT)) {
            scano[0] = (unsigned)(NBINS - 1 - i) << 20;
            scano[1] = src[i];
        }
    }
}

__global__ __launch_bounds__(256)
void compact_kernel(const float* __restrict__ S, float* __restrict__ ws) {
    const float* rowsum = ws + ROWSUM_OFF / 4;
    const float* colsum = ws + COLSUM_OFF / 4;
    unsigned tau = ((unsigned*)ws)[SCAN_OFF / 4];
    int* counter = (int*)ws + CNT_OFF / 4;
    float* candv = ws + CANDV_OFF / 4;
    int* candi = (int*)ws + CANDI_OFF / 4;
    const float4* S4 = (const float4*)S;
    int gtid = blockIdx.x * 256 + threadIdx.x;
    const int total4 = Nn * Mm / 4;
    for (int idx = gtid; idx < total4; idx += gridDim.x * 256) {
        float4 v = S4[idx];
        int lin = idx * 4;
        int i = lin >> 12, j = lin & 4095;
        float ri = 1.0f / rowsum[i];
        float4 cv = *(const float4*)&colsum[j];
        float f[4] = {(v.x * ri) * (v.x / cv.x), (v.y * ri) * (v.y / cv.y),
                      (v.z * ri) * (v.z / cv.z), (v.w * ri) * (v.w / cv.w)};
        #pragma unroll
        for (int q = 0; q < 4; ++q) {
            if (__float_as_uint(f[q]) >= tau) {
                int p = atomicAdd(counter, 1);
                if (p < CAP) {
                    candv[p] = f[q];
                    candi[p] = lin + q;
                }
            }
        }
    }
}

__global__ __launch_bounds__(1024)
void select_kernel(const float* __restrict__ ws, float* __restrict__ out) {
    const int* counter = (const int*)ws + CNT_OFF / 4;
    const float* candv = ws + CANDV_OFF / 4;
    const int* candi = (const int*)ws + CANDI_OFF / 4;
    int n = *counter;
    if (n > CAP) n = CAP;
    int P = 256;
    while (P < n) P <<= 1;
    __shared__ float v[CAP];
    __shared__ int id[CAP];
    int t = threadIdx.x;
    for (int i = t; i < P; i += 1024) {
        if (i < n) { v[i] = candv[i]; id[i] = candi[i]; }
        else       { v[i] = -1.0f;    id[i] = 0x7fffffff; }
    }
    __syncthreads();
    for (int k = 2; k <= P; k <<= 1) {
        for (int j = k >> 1; j > 0; j >>= 1) {
            for (int i = t; i < P; i += 1024) {
                int ixj = i ^ j;
                if (ixj > i) {
                    float va = v[i], vb = v[ixj];
                    int ia = id[i], ib = id[ixj];
                    bool aFirst = (va > vb) || (va == vb && ia < ib);
                    bool up = ((i & k) == 0);
                    if (up ? !aFirst : aFirst) {
                        v[i] = vb; v[ixj] = va;
                        id[i] = ib; id[ixj] = ia;
                    }
                }
            }
            __syncthreads();
        }
    }
    if (t < KOUT) {
        int idx = id[t];
        out[t]            = (float)(idx >> 12);
        out[KOUT + t]     = (float)(idx & (Mm - 1));
        out[2 * KOUT + t] = v[t];
    }
}

extern "C" void kernel_launch(void* const* d_in, const int* in_sizes, int n_in,
                              void* d_out, int out_size, void* d_ws, size_t ws_size,
                              hipStream_t stream) {
    const float* rf = (const float*)d_in[0];
    const float* sf = (const float*)d_in[1];
    const float* re = (const float*)d_in[2];
    const float* se = (const float*)d_in[3];
    float* ws = (float*)d_ws;
    float* out = (float*)d_out;

    zero_kernel<<<17, 256, 0, stream>>>((unsigned*)d_ws);
    norms_kernel<<<Nn + Mm, 64, 0, stream>>>(re, se, ws);

    if (ws_size >= NEW_REQ) {
        unsigned short* AH = (unsigned short*)((char*)d_ws + AH_OFF);
        unsigned short* AL = (unsigned short*)((char*)d_ws + AL_OFF);
        unsigned short* BH = (unsigned short*)((char*)d_ws + BH_OFF);
        unsigned short* BL = (unsigned short*)((char*)d_ws + BL_OFF);
        float* S = ws + SNEW_OFF / 4;
        prep_kernel<<<1024, 256, 0, stream>>>(rf, sf, re, se, AH, AL, BH, BL);
        mfma_gemm_kernel<<<dim3(32, 32), 256, 0, stream>>>(
            (const __bf16*)AH, (const __bf16*)AL, (const __bf16*)BH, (const __bf16*)BL, ws, S);
        partred32_kernel<<<16, 256, 0, stream>>>(ws);
        hist_kernel<<<1024, 256, 0, stream>>>(S, ws);
        scan_kernel<<<1, 1024, 0, stream>>>(ws);
        compact_kernel<<<1024, 256, 0, stream>>>(S, ws);
    } else if (ws_size >= FAST_REQ) {
        float* S = ws + S_OFF / 4;
        dim3 tgrid(Mm / 64, Nn / 64);
        tile_kernel<0><<<tgrid, 256, 0, stream>>>(rf, sf, re, se, ws);
        rowsum_kernel<<<Nn, 256, 0, stream>>>(S, ws);
        colsum_kernel<<<Mm / 64, 256, 0, stream>>>(S, ws);
        hist_kernel<<<1024, 256, 0, stream>>>(S, ws);
        scan_kernel<<<1, 1024, 0, stream>>>(ws);
        compact_kernel<<<1024, 256, 0, stream>>>(S, ws);
    } else {
        dim3 tgrid(Mm / 64, Nn / 64);
        tile_kernel<1><<<tgrid, 256, 0, stream>>>(rf, sf, re, se, ws);
        partred_kernel<<<16, 256, 0, stream>>>(ws);
        tile_kernel<2><<<tgrid, 256, 0, stream>>>(rf, sf, re, se, ws);
        scan_kernel<<<1, 1024, 0, stream>>>(ws);
        tile_kernel<3><<<tgrid, 256, 0, stream>>>(rf, sf, re, se, ws);
    }
    select_kernel<<<1, 1024, 0, stream>>>(ws, out);
}

// Round 5
// 169.615 us; speedup vs baseline: 1.7888x; 1.7888x over previous
//
#include <hip/hip_runtime.h>

#define Nn 4096
#define Mm 4096
#define Dd 512
#define Ee 128
#define KOUT 256
#define NBINS 4096
#define CAP 4096

// ---- workspace layout (bytes) ----
#define ROWSUM_OFF 0
#define COLSUM_OFF 16384
#define REN2_OFF   32768
#define SEN2_OFF   49152
#define HIST_OFF   65536
#define SCAN_OFF   81920
#define CNT_OFF    81928
#define CANDV_OFF  98304
#define CANDI_OFF  114688
// new path partials [4096][32] f32
#define RP32_OFF   131072
#define CP32_OFF   655360
// old fallback partials [4096][64]
#define ROWPART_OFF 131072
#define COLPART_OFF (131072 + 1048576)
// bf16 split arrays, staging-tiled layout: each 4096*640*2 = 5 MB
#define AH_OFF   4194304
#define AL_OFF   (AH_OFF + 5242880)
#define BH_OFF   (AL_OFF + 5242880)
#define BL_OFF   (BH_OFF + 5242880)
#define SNEW_OFF 25165824            // 24 MB, S = 64 MB -> ends 88 MB
#define NEW_REQ  ((size_t)SNEW_OFF + (size_t)Nn * Mm * 4)
// old fallback S at 4 MB
#define S_OFF      4194304
#define FAST_REQ   ((size_t)S_OFF + (size_t)Nn * Mm * 4)

typedef float f32x4 __attribute__((ext_vector_type(4)));
typedef __bf16 bf16x8 __attribute__((ext_vector_type(8)));

__global__ __launch_bounds__(256)
void zero_kernel(unsigned* __restrict__ wsu) {
    int i = blockIdx.x * 256 + threadIdx.x;
    if (i < NBINS + 3) wsu[HIST_OFF / 4 + i] = 0;
}

__global__ __launch_bounds__(64)
void norms_kernel(const float* __restrict__ re, const float* __restrict__ se,
                  float* __restrict__ ws) {
    int row = blockIdx.x;
    int t = threadIdx.x;
    const float* p = (row < Nn) ? (re + (size_t)row * Ee) : (se + (size_t)(row - Nn) * Ee);
    float x0 = p[t], x1 = p[t + 64];
    float v = x0 * x0 + x1 * x1;
    #pragma unroll
    for (int o = 32; o > 0; o >>= 1) v += __shfl_down(v, o);
    if (t == 0) {
        if (row < Nn) ws[REN2_OFF / 4 + row] = v;
        else          ws[SEN2_OFF / 4 + row - Nn] = v;
    }
}

// ---------------- MFMA path ----------------

__device__ __forceinline__ unsigned short b16rtn(float x) {
    unsigned u = __float_as_uint(x);
    return (unsigned short)((u + 0x7fffu + ((u >> 16) & 1u)) >> 16);
}
__device__ __forceinline__ void split1(float x, unsigned short& h, unsigned short& l) {
    h = b16rtn(x);
    float hf = __uint_as_float((unsigned)h << 16);
    l = b16rtn(x - hf);
}

// staging-tiled packed index: [row/128][k/32][ (k/8)%4 ][row%128][k%8]
__device__ __forceinline__ size_t pkidx(int row, int k) {
    return ((size_t)(row >> 7) * 20 + (k >> 5)) * 4096
         + (size_t)(((k >> 3) & 3) * 1024 + (row & 127) * 8 + (k & 7));
}

__global__ __launch_bounds__(256)
void prep_kernel(const float* __restrict__ rf, const float* __restrict__ sf,
                 const float* __restrict__ re, const float* __restrict__ se,
                 unsigned short* __restrict__ AH, unsigned short* __restrict__ AL,
                 unsigned short* __restrict__ BH, unsigned short* __restrict__ BL) {
    int gt = blockIdx.x * 256 + threadIdx.x;
    int nth = gridDim.x * 256;
    const float4* rf4 = (const float4*)rf;
    const float4* sf4 = (const float4*)sf;
    for (int i = gt; i < Nn * Dd / 4; i += nth) {
        int r = i >> 7, k = (i & 127) * 4;
        size_t o = pkidx(r, k);
        float4 a = rf4[i];
        ushort4 h, l;
        split1(a.x, h.x, l.x); split1(a.y, h.y, l.y);
        split1(a.z, h.z, l.z); split1(a.w, h.w, l.w);
        *(ushort4*)&AH[o] = h; *(ushort4*)&AL[o] = l;
        float4 b = sf4[i];
        split1(b.x, h.x, l.x); split1(b.y, h.y, l.y);
        split1(b.z, h.z, l.z); split1(b.w, h.w, l.w);
        *(ushort4*)&BH[o] = h; *(ushort4*)&BL[o] = l;
    }
    const float4* re4 = (const float4*)re;
    const float4* se4 = (const float4*)se;
    for (int i = gt; i < Nn * Ee / 4; i += nth) {
        int r = i >> 5, k = Dd + (i & 31) * 4;
        size_t o = pkidx(r, k);
        float4 a = re4[i];
        ushort4 h, l;
        split1(a.x, h.x, l.x); split1(a.y, h.y, l.y);
        split1(a.z, h.z, l.z); split1(a.w, h.w, l.w);
        *(ushort4*)&AH[o] = h; *(ushort4*)&AL[o] = l;
        float4 b = se4[i];
        split1(0.1f * b.x, h.x, l.x); split1(0.1f * b.y, h.y, l.y);
        split1(0.1f * b.z, h.z, l.z); split1(0.1f * b.w, h.w, l.w);
        *(ushort4*)&BH[o] = h; *(ushort4*)&BL[o] = l;
    }
}

__device__ __forceinline__ void gload16(const void* g, void* l) {
    __builtin_amdgcn_global_load_lds((const __attribute__((address_space(1))) unsigned*)g,
                                     (__attribute__((address_space(3))) unsigned*)l, 16, 0, 0);
}

// Logical K = 1920: kt in [0,20) -> AH.BH, [20,40) -> AL.BH, [40,60) -> AH.BL.
// Staging: per K-step, A-tile and B-tile are 8KB contiguous streams (packed layout).
__global__ __launch_bounds__(256, 3)
void mfma_gemm_kernel(const __bf16* __restrict__ AH, const __bf16* __restrict__ AL,
                      const __bf16* __restrict__ BH, const __bf16* __restrict__ BL,
                      float* __restrict__ ws, float* __restrict__ S) {
    __shared__ __bf16 lds[2][2][4096];   // [dbuf][A/B][g*1024 + r*8 + e]  = 32 KB
    const int tid = threadIdx.x;
    const int lane = tid & 63, wid = tid >> 6;
    const int bx = blockIdx.x, by = blockIdx.y;
    const int rowbase = by * 128, colbase = bx * 128;
    const int wr = wid >> 1, wc = wid & 1;

    f32x4 acc[4][4];
    #pragma unroll
    for (int i = 0; i < 4; ++i)
        #pragma unroll
        for (int j = 0; j < 4; ++j) acc[i][j] = (f32x4){0.f, 0.f, 0.f, 0.f};

    auto stage = [&](int buf, int kt) {
        const int seg = (kt >= 40) ? 2 : (kt >= 20) ? 1 : 0;
        const int t = kt - seg * 20;
        const __bf16* asrc = (seg == 1) ? AL : AH;
        const __bf16* bsrc = (seg == 2) ? BL : BH;
        const __bf16* pa = asrc + ((size_t)by * 20 + t) * 4096;
        const __bf16* pb = bsrc + ((size_t)bx * 20 + t) * 4096;
        #pragma unroll
        for (int q = 0; q < 4; ++q) {
            int flat = wid * 4 + q;          // 0..15
            int arr = flat >> 3;             // 0=A, 1=B
            int chunk = flat & 7;            // 512-elem (1KB) chunk
            const __bf16* s = (arr ? pb : pa) + chunk * 512 + lane * 8;
            gload16(s, (void*)&lds[buf][arr][chunk * 512]);
        }
    };

    stage(0, 0);
    const int g = lane >> 4, c = lane & 15;
    for (int kt = 0; kt < 60; ++kt) {
        const int buf = kt & 1;
        __syncthreads();
        if (kt + 1 < 60) stage(buf ^ 1, kt + 1);
        const __bf16* Asl = &lds[buf][0][0];
        const __bf16* Bsl = &lds[buf][1][0];
        bf16x8 a[4], b[4];
        #pragma unroll
        for (int mi = 0; mi < 4; ++mi)
            a[mi] = *(const bf16x8*)&Asl[(g * 128 + wr * 64 + mi * 16 + c) * 8];
        #pragma unroll
        for (int ni = 0; ni < 4; ++ni)
            b[ni] = *(const bf16x8*)&Bsl[(g * 128 + wc * 64 + ni * 16 + c) * 8];
        #pragma unroll
        for (int mi = 0; mi < 4; ++mi)
            #pragma unroll
            for (int ni = 0; ni < 4; ++ni)
                acc[mi][ni] = __builtin_amdgcn_mfma_f32_16x16x32_bf16(a[mi], b[ni], acc[mi][ni], 0, 0, 0);
    }
    __syncthreads();

    // epilogue: s = exp(acc - 0.05*(rn+cn) - 1); deterministic row/col partial sums; write S
    float ren2v[4][4], sen2v[4];
    #pragma unroll
    for (int mi = 0; mi < 4; ++mi)
        #pragma unroll
        for (int q = 0; q < 4; ++q)
            ren2v[mi][q] = ws[REN2_OFF / 4 + rowbase + wr * 64 + mi * 16 + g * 4 + q];
    #pragma unroll
    for (int ni = 0; ni < 4; ++ni)
        sen2v[ni] = ws[SEN2_OFF / 4 + colbase + wc * 64 + ni * 16 + c];

    float* red = (float*)&lds[0][0][0];

    float colacc[4] = {0.f, 0.f, 0.f, 0.f};
    #pragma unroll
    for (int mi = 0; mi < 4; ++mi) {
        float rowacc[4] = {0.f, 0.f, 0.f, 0.f};
        #pragma unroll
        for (int ni = 0; ni < 4; ++ni) {
            #pragma unroll
            for (int q = 0; q < 4; ++q) {
                float e = acc[mi][ni][q] - 0.05f * (ren2v[mi][q] + sen2v[ni]) - 1.0f;
                float s = expf(e);
                acc[mi][ni][q] = s;
                rowacc[q] += s;
                colacc[ni] += s;
            }
        }
        #pragma unroll
        for (int q = 0; q < 4; ++q) {
            float v = rowacc[q];
            v += __shfl_xor(v, 1); v += __shfl_xor(v, 2);
            v += __shfl_xor(v, 4); v += __shfl_xor(v, 8);
            if (c == 0) red[wc * 128 + wr * 64 + mi * 16 + g * 4 + q] = v;
        }
    }
    #pragma unroll
    for (int ni = 0; ni < 4; ++ni) {
        float v = colacc[ni];
        v += __shfl_xor(v, 16); v += __shfl_xor(v, 32);
        if (g == 0) red[256 + wr * 128 + wc * 64 + ni * 16 + c] = v;
    }

    #pragma unroll
    for (int mi = 0; mi < 4; ++mi)
        #pragma unroll
        for (int q = 0; q < 4; ++q) {
            int r = rowbase + wr * 64 + mi * 16 + g * 4 + q;
            #pragma unroll
            for (int ni = 0; ni < 4; ++ni) {
                int cc = colbase + wc * 64 + ni * 16 + c;
                S[(size_t)r * Mm + cc] = acc[mi][ni][q];
            }
        }

    __syncthreads();
    if (tid < 128) {
        ws[RP32_OFF / 4 + (size_t)(rowbase + tid) * 32 + bx] = red[tid] + red[128 + tid];
    } else {
        int t2 = tid - 128;
        ws[CP32_OFF / 4 + (size_t)(colbase + t2) * 32 + by] = red[256 + t2] + red[384 + t2];
    }
}

__global__ __launch_bounds__(256)
void partred32_kernel(float* __restrict__ w) {
    int i = blockIdx.x * 256 + threadIdx.x;
    const float* rp = w + RP32_OFF / 4 + (size_t)i * 32;
    const float* cp = w + CP32_OFF / 4 + (size_t)i * 32;
    float a = 0.f, b = 0.f;
    #pragma unroll
    for (int k = 0; k < 32; ++k) { a += rp[k]; b += cp[k]; }
    w[ROWSUM_OFF / 4 + i] = a;
    w[COLSUM_OFF / 4 + i] = b;
}

// ---------------- old f32 fallback path (proven R2) ----------------

template <int MODE>
__global__ __launch_bounds__(256)
void tile_kernel(const float* __restrict__ rf, const float* __restrict__ sf,
                 const float* __restrict__ re, const float* __restrict__ se,
                 float* __restrict__ ws) {
    const int bx = blockIdx.x, by = blockIdx.y;
    const int tid = threadIdx.x;
    const int tx = tid & 15, ty = tid >> 4;
    const int rowbase = by * 64, colbase = bx * 64;

    __shared__ float As[16][68];
    __shared__ float Bs[16][68];

    float acc1[4][4] = {};
    float acc2[4][4] = {};

    for (int kk = 0; kk < Dd; kk += 16) {
        #pragma unroll
        for (int i = 0; i < 4; ++i) {
            int f = tid + i * 256;
            int r = f >> 4, c = f & 15;
            As[c][r] = rf[(size_t)(rowbase + r) * Dd + kk + c];
            Bs[c][r] = sf[(size_t)(colbase + r) * Dd + kk + c];
        }
        __syncthreads();
        #pragma unroll
        for (int k = 0; k < 16; ++k) {
            float a[4], b[4];
            #pragma unroll
            for (int i = 0; i < 4; ++i) a[i] = As[k][ty * 4 + i];
            #pragma unroll
            for (int j = 0; j < 4; ++j) b[j] = Bs[k][tx * 4 + j];
            #pragma unroll
            for (int i = 0; i < 4; ++i)
                #pragma unroll
                for (int j = 0; j < 4; ++j)
                    acc1[i][j] = fmaf(a[i], b[j], acc1[i][j]);
        }
        __syncthreads();
    }
    for (int kk = 0; kk < Ee; kk += 16) {
        #pragma unroll
        for (int i = 0; i < 4; ++i) {
            int f = tid + i * 256;
            int r = f >> 4, c = f & 15;
            As[c][r] = re[(size_t)(rowbase + r) * Ee + kk + c];
            Bs[c][r] = se[(size_t)(colbase + r) * Ee + kk + c];
        }
        __syncthreads();
        #pragma unroll
        for (int k = 0; k < 16; ++k) {
            float a[4], b[4];
            #pragma unroll
            for (int i = 0; i < 4; ++i) a[i] = As[k][ty * 4 + i];
            #pragma unroll
            for (int j = 0; j < 4; ++j) b[j] = Bs[k][tx * 4 + j];
            #pragma unroll
            for (int i = 0; i < 4; ++i)
                #pragma unroll
                for (int j = 0; j < 4; ++j)
                    acc2[i][j] = fmaf(a[i], b[j], acc2[i][j]);
        }
        __syncthreads();
    }

    const int r0 = rowbase + ty * 4, c0 = colbase + tx * 4;
    float rn[4], cn[4];
    #pragma unroll
    for (int i = 0; i < 4; ++i) rn[i] = ws[REN2_OFF / 4 + r0 + i];
    #pragma unroll
    for (int j = 0; j < 4; ++j) cn[j] = ws[SEN2_OFF / 4 + c0 + j];

    float s[4][4];
    #pragma unroll
    for (int i = 0; i < 4; ++i)
        #pragma unroll
        for (int j = 0; j < 4; ++j) {
            float d1 = fmaxf(2.0f - 2.0f * acc1[i][j], 0.0f);
            float sq = fmaxf(rn[i] + cn[j] - 2.0f * acc2[i][j], 0.0f);
            s[i][j] = expf(-(0.5f * d1 + 0.05f * sq));
        }

    if constexpr (MODE == 0) {
        float* S = ws + S_OFF / 4;
        #pragma unroll
        for (int i = 0; i < 4; ++i) {
            float4 v = make_float4(s[i][0], s[i][1], s[i][2], s[i][3]);
            *(float4*)&S[(size_t)(r0 + i) * Mm + c0] = v;
        }
    }
    if constexpr (MODE == 1) {
        __shared__ float red[64][17];
        #pragma unroll
        for (int i = 0; i < 4; ++i)
            red[ty * 4 + i][tx] = s[i][0] + s[i][1] + s[i][2] + s[i][3];
        __syncthreads();
        if (tid < 64) {
            float t = 0.f;
            #pragma unroll
            for (int k = 0; k < 16; ++k) t += red[tid][k];
            ws[ROWPART_OFF / 4 + (size_t)(rowbase + tid) * 64 + bx] = t;
        }
        __syncthreads();
        #pragma unroll
        for (int j = 0; j < 4; ++j)
            red[tx * 4 + j][ty] = s[0][j] + s[1][j] + s[2][j] + s[3][j];
        __syncthreads();
        if (tid < 64) {
            float t = 0.f;
            #pragma unroll
            for (int k = 0; k < 16; ++k) t += red[tid][k];
            ws[COLPART_OFF / 4 + (size_t)(colbase + tid) * 64 + by] = t;
        }
    }
    if constexpr (MODE == 2) {
        __shared__ unsigned lh[NBINS];
        for (int b = tid; b < NBINS; b += 256) lh[b] = 0;
        __syncthreads();
        float rs[4], cs[4];
        #pragma unroll
        for (int i = 0; i < 4; ++i) rs[i] = ws[ROWSUM_OFF / 4 + r0 + i];
        #pragma unroll
        for (int j = 0; j < 4; ++j) cs[j] = ws[COLSUM_OFF / 4 + c0 + j];
        #pragma unroll
        for (int i = 0; i < 4; ++i)
            #pragma unroll
            for (int j = 0; j < 4; ++j) {
                float f = (s[i][j] / rs[i]) * (s[i][j] / cs[j]);
                atomicAdd(&lh[__float_as_uint(f) >> 20], 1u);
            }
        __syncthreads();
        unsigned* hist = (unsigned*)ws + HIST_OFF / 4;
        for (int b = tid; b < NBINS; b += 256) {
            unsigned cc = lh[b];
            if (cc) atomicAdd(&hist[b], cc);
        }
    }
    if constexpr (MODE == 3) {
        unsigned tau = ((unsigned*)ws)[SCAN_OFF / 4];
        int* counter = (int*)ws + CNT_OFF / 4;
        float* candv = ws + CANDV_OFF / 4;
        int* candi = (int*)ws + CANDI_OFF / 4;
        float rs[4], cs[4];
        #pragma unroll
        for (int i = 0; i < 4; ++i) rs[i] = ws[ROWSUM_OFF / 4 + r0 + i];
        #pragma unroll
        for (int j = 0; j < 4; ++j) cs[j] = ws[COLSUM_OFF / 4 + c0 + j];
        #pragma unroll
        for (int i = 0; i < 4; ++i)
            #pragma unroll
            for (int j = 0; j < 4; ++j) {
                float f = (s[i][j] / rs[i]) * (s[i][j] / cs[j]);
                if (__float_as_uint(f) >= tau) {
                    int p = atomicAdd(counter, 1);
                    if (p < CAP) {
                        candv[p] = f;
                        candi[p] = (r0 + i) * Mm + (c0 + j);
                    }
                }
            }
    }
}

__global__ __launch_bounds__(256)
void partred_kernel(float* __restrict__ w) {
    int i = blockIdx.x * 256 + threadIdx.x;
    const float* rp = w + ROWPART_OFF / 4 + (size_t)i * 64;
    const float* cp = w + COLPART_OFF / 4 + (size_t)i * 64;
    float a = 0.f, b = 0.f;
    #pragma unroll
    for (int k = 0; k < 64; ++k) { a += rp[k]; b += cp[k]; }
    w[ROWSUM_OFF / 4 + i] = a;
    w[COLSUM_OFF / 4 + i] = b;
}

__global__ __launch_bounds__(256)
void rowsum_kernel(const float* __restrict__ S, float* __restrict__ ws) {
    int row = blockIdx.x;
    const float4* p = (const float4*)(S + (size_t)row * Mm);
    float acc = 0.f;
    #pragma unroll
    for (int k = 0; k < 4; ++k) {
        float4 v = p[threadIdx.x + k * 256];
        acc += v.x + v.y + v.z + v.w;
    }
    __shared__ float red[256];
    red[threadIdx.x] = acc;
    __syncthreads();
    for (int o = 128; o > 0; o >>= 1) {
        if (threadIdx.x < o) red[threadIdx.x] += red[threadIdx.x + o];
        __syncthreads();
    }
    if (threadIdx.x == 0) ws[ROWSUM_OFF / 4 + row] = red[0];
}

__global__ __launch_bounds__(256)
void colsum_kernel(const float* __restrict__ S, float* __restrict__ ws) {
    int base = blockIdx.x * 64;
    int c = threadIdx.x & 63, stripe = threadIdx.x >> 6;
    float acc = 0.f;
    for (int r = stripe; r < Nn; r += 4) acc += S[(size_t)r * Mm + base + c];
    __shared__ float red[256];
    red[threadIdx.x] = acc;
    __syncthreads();
    if (threadIdx.x < 64) {
        float t = red[c] + red[c + 64] + red[c + 128] + red[c + 192];
        ws[COLSUM_OFF / 4 + base + c] = t;
    }
}

// ---------------- shared selection pipeline ----------------

__global__ __launch_bounds__(256)
void hist_kernel(const float* __restrict__ S, float* __restrict__ ws) {
    __shared__ unsigned lh[NBINS];
    for (int b = threadIdx.x; b < NBINS; b += 256) lh[b] = 0;
    __syncthreads();
    const float* rowsum = ws + ROWSUM_OFF / 4;
    const float* colsum = ws + COLSUM_OFF / 4;
    unsigned* hist = (unsigned*)ws + HIST_OFF / 4;
    const float4* S4 = (const float4*)S;
    int gtid = blockIdx.x * 256 + threadIdx.x;
    const int total4 = Nn * Mm / 4;
    for (int idx = gtid; idx < total4; idx += gridDim.x * 256) {
        float4 v = S4[idx];
        int lin = idx * 4;
        int i = lin >> 12, j = lin & 4095;
        float ri = 1.0f / rowsum[i];
        float4 cv = *(const float4*)&colsum[j];
        float f0 = (v.x * ri) * (v.x / cv.x);
        float f1 = (v.y * ri) * (v.y / cv.y);
        float f2 = (v.z * ri) * (v.z / cv.z);
        float f3 = (v.w * ri) * (v.w / cv.w);
        atomicAdd(&lh[__float_as_uint(f0) >> 20], 1u);
        atomicAdd(&lh[__float_as_uint(f1) >> 20], 1u);
        atomicAdd(&lh[__float_as_uint(f2) >> 20], 1u);
        atomicAdd(&lh[__float_as_uint(f3) >> 20], 1u);
    }
    __syncthreads();
    for (int b = threadIdx.x; b < NBINS; b += 256) {
        unsigned c = lh[b];
        if (c) atomicAdd(&hist[b], c);
    }
}

__global__ __launch_bounds__(1024)
void scan_kernel(float* __restrict__ ws) {
    unsigned* hist = (unsigned*)ws + HIST_OFF / 4;
    unsigned* scano = (unsigned*)ws + SCAN_OFF / 4;
    __shared__ unsigned A[NBINS], B[NBINS];
    int t = threadIdx.x;
    for (int i = t; i < NBINS; i += 1024) A[i] = hist[NBINS - 1 - i];
    __syncthreads();
    unsigned* src = A;
    unsigned* dst = B;
    for (int st = 1; st < NBINS; st <<= 1) {
        for (int i = t; i < NBINS; i += 1024)
            dst[i] = src[i] + (i >= st ? src[i - st] : 0u);
        __syncthreads();
        unsigned* tmp = src; src = dst; dst = tmp;
    }
    for (int i = t; i < NBINS; i += 1024) {
        if (src[i] >= KOUT && (i == 0 || src[i - 1] < KOUT)) {
            scano[0] = (unsigned)(NBINS - 1 - i) << 20;
            scano[1] = src[i];
        }
    }
}

__global__ __launch_bounds__(256)
void compact_kernel(const float* __restrict__ S, float* __restrict__ ws) {
    const float* rowsum = ws + ROWSUM_OFF / 4;
    const float* colsum = ws + COLSUM_OFF / 4;
    unsigned tau = ((unsigned*)ws)[SCAN_OFF / 4];
    int* counter = (int*)ws + CNT_OFF / 4;
    float* candv = ws + CANDV_OFF / 4;
    int* candi = (int*)ws + CANDI_OFF / 4;
    const float4* S4 = (const float4*)S;
    int gtid = blockIdx.x * 256 + threadIdx.x;
    const int total4 = Nn * Mm / 4;
    for (int idx = gtid; idx < total4; idx += gridDim.x * 256) {
        float4 v = S4[idx];
        int lin = idx * 4;
        int i = lin >> 12, j = lin & 4095;
        float ri = 1.0f / rowsum[i];
        float4 cv = *(const float4*)&colsum[j];
        float f[4] = {(v.x * ri) * (v.x / cv.x), (v.y * ri) * (v.y / cv.y),
                      (v.z * ri) * (v.z / cv.z), (v.w * ri) * (v.w / cv.w)};
        #pragma unroll
        for (int q = 0; q < 4; ++q) {
            if (__float_as_uint(f[q]) >= tau) {
                int p = atomicAdd(counter, 1);
                if (p < CAP) {
                    candv[p] = f[q];
                    candi[p] = lin + q;
                }
            }
        }
    }
}

__global__ __launch_bounds__(1024)
void select_kernel(const float* __restrict__ ws, float* __restrict__ out) {
    const int* counter = (const int*)ws + CNT_OFF / 4;
    const float* candv = ws + CANDV_OFF / 4;
    const int* candi = (const int*)ws + CANDI_OFF / 4;
    int n = *counter;
    if (n > CAP) n = CAP;
    int P = 256;
    while (P < n) P <<= 1;
    __shared__ float v[CAP];
    __shared__ int id[CAP];
    int t = threadIdx.x;
    for (int i = t; i < P; i += 1024) {
        if (i < n) { v[i] = candv[i]; id[i] = candi[i]; }
        else       { v[i] = -1.0f;    id[i] = 0x7fffffff; }
    }
    __syncthreads();
    for (int k = 2; k <= P; k <<= 1) {
        for (int j = k >> 1; j > 0; j >>= 1) {
            for (int i = t; i < P; i += 1024) {
                int ixj = i ^ j;
                if (ixj > i) {
                    float va = v[i], vb = v[ixj];
                    int ia = id[i], ib = id[ixj];
                    bool aFirst = (va > vb) || (va == vb && ia < ib);
                    bool up = ((i & k) == 0);
                    if (up ? !aFirst : aFirst) {
                        v[i] = vb; v[ixj] = va;
                        id[i] = ib; id[ixj] = ia;
                    }
                }
            }
            __syncthreads();
        }
    }
    if (t < KOUT) {
        int idx = id[t];
        out[t]            = (float)(idx >> 12);
        out[KOUT + t]     = (float)(idx & (Mm - 1));
        out[2 * KOUT + t] = v[t];
    }
}

extern "C" void kernel_launch(void* const* d_in, const int* in_sizes, int n_in,
                              void* d_out, int out_size, void* d_ws, size_t ws_size,
                              hipStream_t stream) {
    const float* rf = (const float*)d_in[0];
    const float* sf = (const float*)d_in[1];
    const float* re = (const float*)d_in[2];
    const float* se = (const float*)d_in[3];
    float* ws = (float*)d_ws;
    float* out = (float*)d_out;

    zero_kernel<<<17, 256, 0, stream>>>((unsigned*)d_ws);
    norms_kernel<<<Nn + Mm, 64, 0, stream>>>(re, se, ws);

    if (ws_size >= NEW_REQ) {
        unsigned short* AH = (unsigned short*)((char*)d_ws + AH_OFF);
        unsigned short* AL = (unsigned short*)((char*)d_ws + AL_OFF);
        unsigned short* BH = (unsigned short*)((char*)d_ws + BH_OFF);
        unsigned short* BL = (unsigned short*)((char*)d_ws + BL_OFF);
        float* S = ws + SNEW_OFF / 4;
        prep_kernel<<<1024, 256, 0, stream>>>(rf, sf, re, se, AH, AL, BH, BL);
        mfma_gemm_kernel<<<dim3(32, 32), 256, 0, stream>>>(
            (const __bf16*)AH, (const __bf16*)AL, (const __bf16*)BH, (const __bf16*)BL, ws, S);
        partred32_kernel<<<16, 256, 0, stream>>>(ws);
        hist_kernel<<<1024, 256, 0, stream>>>(S, ws);
        scan_kernel<<<1, 1024, 0, stream>>>(ws);
        compact_kernel<<<1024, 256, 0, stream>>>(S, ws);
    } else if (ws_size >= FAST_REQ) {
        float* S = ws + S_OFF / 4;
        dim3 tgrid(Mm / 64, Nn / 64);
        tile_kernel<0><<<tgrid, 256, 0, stream>>>(rf, sf, re, se, ws);
        rowsum_kernel<<<Nn, 256, 0, stream>>>(S, ws);
        colsum_kernel<<<Mm / 64, 256, 0, stream>>>(S, ws);
        hist_kernel<<<1024, 256, 0, stream>>>(S, ws);
        scan_kernel<<<1, 1024, 0, stream>>>(ws);
        compact_kernel<<<1024, 256, 0, stream>>>(S, ws);
    } else {
        dim3 tgrid(Mm / 64, Nn / 64);
        tile_kernel<1><<<tgrid, 256, 0, stream>>>(rf, sf, re, se, ws);
        partred_kernel<<<16, 256, 0, stream>>>(ws);
        tile_kernel<2><<<tgrid, 256, 0, stream>>>(rf, sf, re, se, ws);
        scan_kernel<<<1, 1024, 0, stream>>>(ws);
        tile_kernel<3><<<tgrid, 256, 0, stream>>>(rf, sf, re, se, ws);
    }
    select_kernel<<<1, 1024, 0, stream>>>(ws, out);
}